// Round 5
// baseline (880.468 us; speedup 1.0000x reference)
//
#include <hip/hip_runtime.h>

#define H 128
#define LDX 132   // padded leading dim for the LDS node-row tile (conflict-free column reads)

// ---- degree count: cnt[dst[e]] += 1 ----
__global__ void deg_kernel(const int* __restrict__ dst, int* __restrict__ cnt, int ne) {
  int e = blockIdx.x * blockDim.x + threadIdx.x;
  if (e < ne) atomicAdd(&cnt[dst[e]], 1);
}

// ---- dinv[i] = rsqrt(cnt[i] + 1)  (self-loop) ----
__global__ void dinv_kernel(const int* __restrict__ cnt, float* __restrict__ dinv, int n) {
  int i = blockIdx.x * blockDim.x + threadIdx.x;
  if (i < n) dinv[i] = rsqrtf((float)(cnt[i] + 1));
}

// ---- exclusive scan, stage 1: 1024 elems/block ----
__global__ __launch_bounds__(256) void scan1(const int* __restrict__ in,
                                             int* __restrict__ out,
                                             int* __restrict__ partials, int n) {
  __shared__ int sdata[256];
  int base = blockIdx.x * 1024;
  int t = threadIdx.x;
  int v[4];
  int sum = 0;
#pragma unroll
  for (int j = 0; j < 4; ++j) {
    int idx = base + t * 4 + j;
    v[j] = (idx < n) ? in[idx] : 0;
    sum += v[j];
  }
  sdata[t] = sum;
  __syncthreads();
  for (int off = 1; off < 256; off <<= 1) {
    int y = (t >= off) ? sdata[t - off] : 0;
    __syncthreads();
    sdata[t] += y;
    __syncthreads();
  }
  int excl = sdata[t] - sum;
  int run = excl;
#pragma unroll
  for (int j = 0; j < 4; ++j) {
    int idx = base + t * 4 + j;
    if (idx < n) out[idx] = run;
    run += v[j];
  }
  if (t == 255) partials[blockIdx.x] = sdata[255];
}

// ---- scan stage 2 ----
__global__ __launch_bounds__(256) void scan2(int* __restrict__ partials, int nb) {
  __shared__ int sdata[256];
  int t = threadIdx.x;
  int v = (t < nb) ? partials[t] : 0;
  sdata[t] = v;
  __syncthreads();
  for (int off = 1; off < 256; off <<= 1) {
    int y = (t >= off) ? sdata[t - off] : 0;
    __syncthreads();
    sdata[t] += y;
    __syncthreads();
  }
  if (t < nb) partials[t] = sdata[t] - v;
}

// ---- scan stage 3: add block offsets; duplicate into cursor; set row_start[n] = ne ----
__global__ void scan3(int* __restrict__ out, int* __restrict__ cursor,
                      const int* __restrict__ partials, int n, int ne) {
  int i = blockIdx.x * blockDim.x + threadIdx.x;
  if (i < n) {
    int v = out[i] + partials[i >> 10];
    out[i] = v;
    cursor[i] = v;
  }
  if (i == 0) out[n] = ne;
}

// ---- CSR fill, XCD-partitioned by dst-range for L2 write combining ----
__global__ __launch_bounds__(256) void csr_fill_x(
    const int* __restrict__ src, const int* __restrict__ dst,
    int* __restrict__ cursor, int* __restrict__ csr_src,
    int ne, int range, int slices) {
  int r = blockIdx.x & 7;
  int slice = blockIdx.x >> 3;
  int chunk = (ne + slices - 1) / slices;
  int beg = slice * chunk;
  int end = beg + chunk; if (end > ne) end = ne;
  int lo = r * range;
  int hi = lo + range;
  for (int e = beg + threadIdx.x; e < end; e += 256) {
    int d = dst[e];
    int s = src[e];
    if (d >= lo && d < hi) {
      int p = atomicAdd(&cursor[d], 1);
      csr_src[p] = s;
    }
  }
}

// ---- graph boundaries from sorted batch ----
__global__ void gstart_kernel(const int* __restrict__ batch, int* __restrict__ g_start,
                              int n, int G) {
  int i = blockIdx.x * blockDim.x + threadIdx.x;
  if (i >= n) return;
  int b = batch[i];
  int prev = (i == 0) ? -1 : batch[i - 1];
  for (int g = prev + 1; g <= b; ++g) g_start[g] = i;
  if (i == n - 1) {
    for (int g = b + 1; g <= G; ++g) g_start[g] = n;
  }
}

// ---- unrolled neighbor-row gather (32 lanes per node, float4/lane) ----
__device__ __forceinline__ float4 gather_rows(
    const float* __restrict__ hs, const int* __restrict__ csr_src,
    int beg, int end, int c, float4 acc) {
  int k = beg;
  for (; k + 7 < end; k += 8) {
    int s0 = csr_src[k + 0], s1 = csr_src[k + 1];
    int s2 = csr_src[k + 2], s3 = csr_src[k + 3];
    int s4 = csr_src[k + 4], s5 = csr_src[k + 5];
    int s6 = csr_src[k + 6], s7 = csr_src[k + 7];
    float4 v0 = *(const float4*)(hs + (size_t)s0 * H + c);
    float4 v1 = *(const float4*)(hs + (size_t)s1 * H + c);
    float4 v2 = *(const float4*)(hs + (size_t)s2 * H + c);
    float4 v3 = *(const float4*)(hs + (size_t)s3 * H + c);
    float4 v4 = *(const float4*)(hs + (size_t)s4 * H + c);
    float4 v5 = *(const float4*)(hs + (size_t)s5 * H + c);
    float4 v6 = *(const float4*)(hs + (size_t)s6 * H + c);
    float4 v7 = *(const float4*)(hs + (size_t)s7 * H + c);
    acc.x += ((v0.x + v1.x) + (v2.x + v3.x)) + ((v4.x + v5.x) + (v6.x + v7.x));
    acc.y += ((v0.y + v1.y) + (v2.y + v3.y)) + ((v4.y + v5.y) + (v6.y + v7.y));
    acc.z += ((v0.z + v1.z) + (v2.z + v3.z)) + ((v4.z + v5.z) + (v6.z + v7.z));
    acc.w += ((v0.w + v1.w) + (v2.w + v3.w)) + ((v4.w + v5.w) + (v6.w + v7.w));
  }
  for (; k < end; ++k) {
    int s = csr_src[k];
    float4 v = *(const float4*)(hs + (size_t)s * H + c);
    acc.x += v.x; acc.y += v.y; acc.z += v.z; acc.w += v.w;
  }
  return acc;
}

// ---- layer-1 GEMM: out[r][c] = (X @ W)[r][c] * dinv[r] ----
__global__ __launch_bounds__(256) void gemm_scale(
    const float* __restrict__ X, const float* __restrict__ W,
    const float* __restrict__ dinv, float* __restrict__ out, int n) {
  __shared__ float sXT[16][64];
  __shared__ float sW[16][H];
  int tid = threadIdx.x;
  int row0 = blockIdx.x * 64;
  int rg = tid >> 5;
  int cg = (tid & 31) << 2;

  float acc[8][4];
#pragma unroll
  for (int r = 0; r < 8; ++r) { acc[r][0]=0.f; acc[r][1]=0.f; acc[r][2]=0.f; acc[r][3]=0.f; }

  int xrow = tid >> 2;
  int xkq  = (tid & 3) << 2;
  int wkk  = tid >> 4;
  int wc   = (tid & 15) << 3;

  for (int k0 = 0; k0 < H; k0 += 16) {
    {
      int r = row0 + xrow;
      float4 v = make_float4(0.f, 0.f, 0.f, 0.f);
      if (r < n) v = *(const float4*)(X + (size_t)r * H + k0 + xkq);
      sXT[xkq + 0][xrow] = v.x;
      sXT[xkq + 1][xrow] = v.y;
      sXT[xkq + 2][xrow] = v.z;
      sXT[xkq + 3][xrow] = v.w;
    }
    {
      const float* wp = W + (size_t)(k0 + wkk) * H + wc;
      *(float4*)&sW[wkk][wc]     = *(const float4*)(wp);
      *(float4*)&sW[wkk][wc + 4] = *(const float4*)(wp + 4);
    }
    __syncthreads();
#pragma unroll
    for (int kk = 0; kk < 16; ++kk) {
      float4 wv = *(float4*)&sW[kk][cg];
      float4 a0 = *(float4*)&sXT[kk][rg * 8];
      float4 a1 = *(float4*)&sXT[kk][rg * 8 + 4];
      acc[0][0] = fmaf(a0.x, wv.x, acc[0][0]); acc[0][1] = fmaf(a0.x, wv.y, acc[0][1]);
      acc[0][2] = fmaf(a0.x, wv.z, acc[0][2]); acc[0][3] = fmaf(a0.x, wv.w, acc[0][3]);
      acc[1][0] = fmaf(a0.y, wv.x, acc[1][0]); acc[1][1] = fmaf(a0.y, wv.y, acc[1][1]);
      acc[1][2] = fmaf(a0.y, wv.z, acc[1][2]); acc[1][3] = fmaf(a0.y, wv.w, acc[1][3]);
      acc[2][0] = fmaf(a0.z, wv.x, acc[2][0]); acc[2][1] = fmaf(a0.z, wv.y, acc[2][1]);
      acc[2][2] = fmaf(a0.z, wv.z, acc[2][2]); acc[2][3] = fmaf(a0.z, wv.w, acc[2][3]);
      acc[3][0] = fmaf(a0.w, wv.x, acc[3][0]); acc[3][1] = fmaf(a0.w, wv.y, acc[3][1]);
      acc[3][2] = fmaf(a0.w, wv.z, acc[3][2]); acc[3][3] = fmaf(a0.w, wv.w, acc[3][3]);
      acc[4][0] = fmaf(a1.x, wv.x, acc[4][0]); acc[4][1] = fmaf(a1.x, wv.y, acc[4][1]);
      acc[4][2] = fmaf(a1.x, wv.z, acc[4][2]); acc[4][3] = fmaf(a1.x, wv.w, acc[4][3]);
      acc[5][0] = fmaf(a1.y, wv.x, acc[5][0]); acc[5][1] = fmaf(a1.y, wv.y, acc[5][1]);
      acc[5][2] = fmaf(a1.y, wv.z, acc[5][2]); acc[5][3] = fmaf(a1.y, wv.w, acc[5][3]);
      acc[6][0] = fmaf(a1.z, wv.x, acc[6][0]); acc[6][1] = fmaf(a1.z, wv.y, acc[6][1]);
      acc[6][2] = fmaf(a1.z, wv.z, acc[6][2]); acc[6][3] = fmaf(a1.z, wv.w, acc[6][3]);
      acc[7][0] = fmaf(a1.w, wv.x, acc[7][0]); acc[7][1] = fmaf(a1.w, wv.y, acc[7][1]);
      acc[7][2] = fmaf(a1.w, wv.z, acc[7][2]); acc[7][3] = fmaf(a1.w, wv.w, acc[7][3]);
    }
    __syncthreads();
  }
#pragma unroll
  for (int r = 0; r < 8; ++r) {
    int row = row0 + rg * 8 + r;
    if (row < n) {
      float dv = dinv[row];
      float4 o;
      o.x = acc[r][0] * dv; o.y = acc[r][1] * dv;
      o.z = acc[r][2] * dv; o.w = acc[r][3] * dv;
      *(float4*)(out + (size_t)row * H + cg) = o;
    }
  }
}

// ---- FUSED: h = relu(dinv*(gather+self)+bprev); out = (h @ W) * dinv ----
// Block owns 64 dst rows. Phase 1: gather -> LDS tile. Phase 2: GEMM from LDS.
__global__ __launch_bounds__(256) void agg_gemm(
    const float* __restrict__ hs, const int* __restrict__ row_start,
    const int* __restrict__ csr_src, const float* __restrict__ dinv,
    const float* __restrict__ bprev, const float* __restrict__ W,
    float* __restrict__ out, int n) {
  __shared__ float sX[64][LDX];   // gathered h rows (post-relu), padded
  __shared__ float sW[16][H];
  int tid = threadIdx.x;
  int row0 = blockIdx.x * 64;
  int c = (tid & 31) << 2;

  // ---- phase 1: gather 64 rows (8 per sub-iteration, 32 lanes/node) ----
#pragma unroll 1
  for (int sub = 0; sub < 8; ++sub) {
    int local = sub * 8 + (tid >> 5);
    int node = row0 + local;
    if (node < n) {
      float4 acc = *(const float4*)(hs + (size_t)node * H + c);  // self-loop
      int beg = row_start[node];
      int end = row_start[node + 1];
      acc = gather_rows(hs, csr_src, beg, end, c, acc);
      float dv = dinv[node];
      float4 bb = *(const float4*)(bprev + c);
      float4 o;
      o.x = fmaxf(fmaf(acc.x, dv, bb.x), 0.f);
      o.y = fmaxf(fmaf(acc.y, dv, bb.y), 0.f);
      o.z = fmaxf(fmaf(acc.z, dv, bb.z), 0.f);
      o.w = fmaxf(fmaf(acc.w, dv, bb.w), 0.f);
      *(float4*)&sX[local][c] = o;
    } else {
      *(float4*)&sX[local][c] = make_float4(0.f, 0.f, 0.f, 0.f);
    }
  }

  // ---- phase 2: 64x128 tile GEMM vs W (staged 16 k-rows at a time) ----
  int rg = tid >> 5;
  int wkk = tid >> 4;
  int wc  = (tid & 15) << 3;

  float acc[8][4];
#pragma unroll
  for (int r = 0; r < 8; ++r) { acc[r][0]=0.f; acc[r][1]=0.f; acc[r][2]=0.f; acc[r][3]=0.f; }

  for (int k0 = 0; k0 < H; k0 += 16) {
    {
      const float* wp = W + (size_t)(k0 + wkk) * H + wc;
      *(float4*)&sW[wkk][wc]     = *(const float4*)(wp);
      *(float4*)&sW[wkk][wc + 4] = *(const float4*)(wp + 4);
    }
    __syncthreads();
#pragma unroll
    for (int kk = 0; kk < 16; ++kk) {
      float4 wv = *(float4*)&sW[kk][c];
#pragma unroll
      for (int r = 0; r < 8; ++r) {
        float xv = sX[rg * 8 + r][k0 + kk];
        acc[r][0] = fmaf(xv, wv.x, acc[r][0]);
        acc[r][1] = fmaf(xv, wv.y, acc[r][1]);
        acc[r][2] = fmaf(xv, wv.z, acc[r][2]);
        acc[r][3] = fmaf(xv, wv.w, acc[r][3]);
      }
    }
    __syncthreads();
  }
#pragma unroll
  for (int r = 0; r < 8; ++r) {
    int row = row0 + rg * 8 + r;
    if (row < n) {
      float dv = dinv[row];
      float4 o;
      o.x = acc[r][0] * dv; o.y = acc[r][1] * dv;
      o.z = acc[r][2] * dv; o.w = acc[r][3] * dv;
      *(float4*)(out + (size_t)row * H + c) = o;
    }
  }
}

// ---- final aggregate (no relu, no trailing GEMM) ----
__global__ __launch_bounds__(256) void aggregate_last(
    const float* __restrict__ hs, const int* __restrict__ row_start,
    const int* __restrict__ csr_src, const float* __restrict__ dinv,
    const float* __restrict__ b, float* __restrict__ out, int n) {
  int node = blockIdx.x * 8 + (threadIdx.x >> 5);
  if (node >= n) return;
  int c = (threadIdx.x & 31) << 2;
  int beg = row_start[node];
  int end = row_start[node + 1];
  float4 acc = *(const float4*)(hs + (size_t)node * H + c);
  acc = gather_rows(hs, csr_src, beg, end, c, acc);
  float dv = dinv[node];
  float4 bb = *(const float4*)(b + c);
  float4 o;
  o.x = fmaf(acc.x, dv, bb.x);
  o.y = fmaf(acc.y, dv, bb.y);
  o.z = fmaf(acc.z, dv, bb.z);
  o.w = fmaf(acc.w, dv, bb.w);
  *(float4*)(out + (size_t)node * H + c) = o;
}

// ---- segmented pooling: one block per graph ----
__global__ __launch_bounds__(256) void pool2(
    const float* __restrict__ h, const int* __restrict__ g_start,
    float* __restrict__ gmean, float* __restrict__ gmax, int n) {
  __shared__ float ssum[8][H];
  __shared__ float smax[8][H];
  int g = blockIdx.x;
  int beg = g_start[g];
  int end = g_start[g + 1];
  int q = threadIdx.x >> 5;
  int c = (threadIdx.x & 31) << 2;

  float4 s = make_float4(0.f, 0.f, 0.f, 0.f);
  float4 m = make_float4(-INFINITY, -INFINITY, -INFINITY, -INFINITY);
  for (int node = beg + q; node < end; node += 8) {
    float4 v = *(const float4*)(h + (size_t)node * H + c);
    s.x += v.x; s.y += v.y; s.z += v.z; s.w += v.w;
    m.x = fmaxf(m.x, v.x); m.y = fmaxf(m.y, v.y);
    m.z = fmaxf(m.z, v.z); m.w = fmaxf(m.w, v.w);
  }
  *(float4*)&ssum[q][c] = s;
  *(float4*)&smax[q][c] = m;
  __syncthreads();

  int cnt = end - beg;
  float inv = 1.0f / fmaxf((float)cnt, 1.0f);
  int t = threadIdx.x;
  if (t < H) {
    float tot = 0.f;
#pragma unroll
    for (int qq = 0; qq < 8; ++qq) tot += ssum[qq][t];
    gmean[(size_t)g * H + t] = tot * inv;
  } else {
    int cc = t - H;
    float mx = -INFINITY;
#pragma unroll
    for (int qq = 0; qq < 8; ++qq) mx = fmaxf(mx, smax[qq][cc]);
    gmax[(size_t)g * H + cc] = (cnt == 0) ? 0.0f : mx;
  }
}

// ---- classifier: one block per graph ----
__global__ __launch_bounds__(128) void classify_kernel(
    const float* __restrict__ gmean, const float* __restrict__ gmax,
    const float* __restrict__ Wc1, const float* __restrict__ bc1,
    const float* __restrict__ Wc2, const float* __restrict__ bc2,
    float* __restrict__ out) {
  __shared__ float gv[2 * H];
  __shared__ float hid[H];
  int gid = blockIdx.x;
  int t = threadIdx.x;
  gv[t] = gmean[(size_t)gid * H + t];
  gv[H + t] = gmax[(size_t)gid * H + t];
  __syncthreads();
  float acc = 0.f;
#pragma unroll 8
  for (int k = 0; k < 2 * H; ++k) acc = fmaf(gv[k], Wc1[(size_t)k * H + t], acc);
  hid[t] = fmaxf(acc + bc1[t], 0.f);
  __syncthreads();
  if (t < 10) {
    float a2 = 0.f;
    for (int j = 0; j < H; ++j) a2 = fmaf(hid[j], Wc2[(size_t)j * 10 + t], a2);
    out[(size_t)gid * 10 + t] = a2 + bc2[t];
  }
}

extern "C" void kernel_launch(void* const* d_in, const int* in_sizes, int n_in,
                              void* d_out, int out_size, void* d_ws, size_t ws_size,
                              hipStream_t stream) {
  const float* x    = (const float*)d_in[0];
  const int* ei     = (const int*)d_in[1];
  const int* batch  = (const int*)d_in[2];
  const float* W1   = (const float*)d_in[3];
  const float* b1   = (const float*)d_in[4];
  const float* W2   = (const float*)d_in[5];
  const float* b2   = (const float*)d_in[6];
  const float* W3   = (const float*)d_in[7];
  const float* b3   = (const float*)d_in[8];
  const float* Wc1  = (const float*)d_in[9];
  const float* bc1  = (const float*)d_in[10];
  const float* Wc2  = (const float*)d_in[11];
  const float* bc2  = (const float*)d_in[12];
  float* out = (float*)d_out;

  const int n  = in_sizes[2];        // 100000 nodes
  const int ne = in_sizes[1] / 2;    // 1600000 edges
  const int G  = 512;
  const size_t NF = (size_t)n * H;

  const int* src = ei;
  const int* dst = ei + ne;

  // ---- workspace layout ----
  float* A = (float*)d_ws;                 // hs ping
  float* B = A + NF;                       // hs pong / final conv output
  char* p = (char*)(B + NF);
  int*      deg_cnt  = (int*)p;       p += (size_t)n * 4;
  float*    dinv     = (float*)p;     p += (size_t)n * 4;
  int*      row_start= (int*)p;       p += (size_t)(n + 1) * 4;
  int*      cursor   = (int*)p;       p += (size_t)n * 4;
  int*      partials = (int*)p;       p += (size_t)256 * 4;
  int*      g_start  = (int*)p;       p += (size_t)(G + 1) * 4;
  float*    gmean    = (float*)p;     p += (size_t)G * H * 4;
  float*    gmax     = (float*)p;     p += (size_t)G * H * 4;
  int*      csr_src  = (int*)p;       p += (size_t)ne * 4;

  hipMemsetAsync(deg_cnt, 0, (size_t)n * 4, stream);

  // ---- CSR build (once, reused by all 3 layers) ----
  deg_kernel<<<(ne + 255) / 256, 256, 0, stream>>>(dst, deg_cnt, ne);
  dinv_kernel<<<(n + 255) / 256, 256, 0, stream>>>(deg_cnt, dinv, n);
  int nb = (n + 1023) / 1024;
  scan1<<<nb, 256, 0, stream>>>(deg_cnt, row_start, partials, n);
  scan2<<<1, 256, 0, stream>>>(partials, nb);
  scan3<<<(n + 255) / 256, 256, 0, stream>>>(row_start, cursor, partials, n, ne);
  {
    int range = (n + 7) / 8;
    int slices = 128;
    csr_fill_x<<<slices * 8, 256, 0, stream>>>(src, dst, cursor, csr_src, ne, range, slices);
  }
  gstart_kernel<<<(n + 255) / 256, 256, 0, stream>>>(batch, g_start, n, G);

  const int tile_grid = (n + 63) / 64;
  const int node_grid = (n + 7) / 8;

  // layer 1 GEMM: A = (x @ W1) * dinv
  gemm_scale<<<tile_grid, 256, 0, stream>>>(x, W1, dinv, A, n);
  // fused: h1 = relu(agg(A)+b1);  B = (h1 @ W2) * dinv
  agg_gemm<<<tile_grid, 256, 0, stream>>>(A, row_start, csr_src, dinv, b1, W2, B, n);
  // fused: h2 = relu(agg(B)+b2);  A = (h2 @ W3) * dinv
  agg_gemm<<<tile_grid, 256, 0, stream>>>(B, row_start, csr_src, dinv, b2, W3, A, n);
  // final: B = agg(A) + b3   (no relu)
  aggregate_last<<<node_grid, 256, 0, stream>>>(A, row_start, csr_src, dinv, b3, B, n);

  // ---- pooling + classifier ----
  pool2<<<G, 256, 0, stream>>>(B, g_start, gmean, gmax, n);
  classify_kernel<<<G, 128, 0, stream>>>(gmean, gmax, Wc1, bc1, Wc2, bc2, out);
}

// Round 6
// 790.310 us; speedup vs baseline: 1.1141x; 1.1141x over previous
//
#include <hip/hip_runtime.h>

#define H 128

// ---- XCD-range-partitioned degree count (L2-local atomics, cf. csr_fill_x) ----
__global__ __launch_bounds__(256) void deg_x(
    const int* __restrict__ dst, int* __restrict__ cnt,
    int ne, int range, int slices) {
  int r = blockIdx.x & 7;
  int slice = blockIdx.x >> 3;
  int chunk = (ne + slices - 1) / slices;
  int beg = slice * chunk;
  int end = beg + chunk; if (end > ne) end = ne;
  int lo = r * range;
  int hi = lo + range;
  for (int e = beg + threadIdx.x; e < end; e += 256) {
    int d = dst[e];
    if (d >= lo && d < hi) atomicAdd(&cnt[d], 1);
  }
}

// ---- dinv[i] = rsqrt(cnt[i] + 1)  (self-loop; TRUE degree) ----
__global__ void dinv_kernel(const int* __restrict__ cnt, float* __restrict__ dinv, int n) {
  int i = blockIdx.x * blockDim.x + threadIdx.x;
  if (i < n) dinv[i] = rsqrtf((float)(cnt[i] + 1));
}

// ---- zero the dummy row (index n) of both hs buffers ----
__global__ void zero_rows(float* __restrict__ A, float* __restrict__ B, int n) {
  int t = threadIdx.x;
  if (t < H) A[(size_t)n * H + t] = 0.f;
  else       B[(size_t)n * H + (t - H)] = 0.f;
}

// ---- init padded CSR storage with dummy index n ----
__global__ void csr_init(int* __restrict__ csr_src, int cap4, int n) {
  int i = blockIdx.x * blockDim.x + threadIdx.x;
  if (i < cap4) *(int4*)(csr_src + i * 4) = make_int4(n, n, n, n);
}

// ---- exclusive scan over PADDED degrees (pad to multiple of 8), stage 1 ----
__global__ __launch_bounds__(256) void scan1(const int* __restrict__ in,
                                             int* __restrict__ out,
                                             int* __restrict__ partials, int n) {
  __shared__ int sdata[256];
  int base = blockIdx.x * 1024;
  int t = threadIdx.x;
  int v[4];
  int sum = 0;
#pragma unroll
  for (int j = 0; j < 4; ++j) {
    int idx = base + t * 4 + j;
    v[j] = (idx < n) ? ((in[idx] + 7) & ~7) : 0;   // padded degree
    sum += v[j];
  }
  sdata[t] = sum;
  __syncthreads();
  for (int off = 1; off < 256; off <<= 1) {
    int y = (t >= off) ? sdata[t - off] : 0;
    __syncthreads();
    sdata[t] += y;
    __syncthreads();
  }
  int excl = sdata[t] - sum;
  int run = excl;
#pragma unroll
  for (int j = 0; j < 4; ++j) {
    int idx = base + t * 4 + j;
    if (idx < n) out[idx] = run;
    run += v[j];
  }
  if (t == 255) partials[blockIdx.x] = sdata[255];
}

// ---- scan stage 2 ----
__global__ __launch_bounds__(256) void scan2(int* __restrict__ partials, int nb) {
  __shared__ int sdata[256];
  int t = threadIdx.x;
  int v = (t < nb) ? partials[t] : 0;
  sdata[t] = v;
  __syncthreads();
  for (int off = 1; off < 256; off <<= 1) {
    int y = (t >= off) ? sdata[t - off] : 0;
    __syncthreads();
    sdata[t] += y;
    __syncthreads();
  }
  if (t < nb) partials[t] = sdata[t] - v;
}

// ---- scan stage 3: add block offsets; dup into cursor; row_start[n] = padded total ----
__global__ void scan3(int* __restrict__ out, int* __restrict__ cursor,
                      const int* __restrict__ deg, const int* __restrict__ partials,
                      int n) {
  int i = blockIdx.x * blockDim.x + threadIdx.x;
  if (i < n) {
    int v = out[i] + partials[i >> 10];
    out[i] = v;
    cursor[i] = v;
    if (i == n - 1) out[n] = v + ((deg[i] + 7) & ~7);
  }
}

// ---- CSR fill, XCD-partitioned by dst-range for L2 write combining ----
__global__ __launch_bounds__(256) void csr_fill_x(
    const int* __restrict__ src, const int* __restrict__ dst,
    int* __restrict__ cursor, int* __restrict__ csr_src,
    int ne, int range, int slices) {
  int r = blockIdx.x & 7;
  int slice = blockIdx.x >> 3;
  int chunk = (ne + slices - 1) / slices;
  int beg = slice * chunk;
  int end = beg + chunk; if (end > ne) end = ne;
  int lo = r * range;
  int hi = lo + range;
  for (int e = beg + threadIdx.x; e < end; e += 256) {
    int d = dst[e];
    int s = src[e];
    if (d >= lo && d < hi) {
      int p = atomicAdd(&cursor[d], 1);
      csr_src[p] = s;
    }
  }
}

// ---- graph boundaries from sorted batch ----
__global__ void gstart_kernel(const int* __restrict__ batch, int* __restrict__ g_start,
                              int n, int G) {
  int i = blockIdx.x * blockDim.x + threadIdx.x;
  if (i >= n) return;
  int b = batch[i];
  int prev = (i == 0) ? -1 : batch[i - 1];
  for (int g = prev + 1; g <= b; ++g) g_start[g] = i;
  if (i == n - 1) {
    for (int g = b + 1; g <= G; ++g) g_start[g] = n;
  }
}

// ---- GEMM: out[r][c] = (X @ W)[r][c] * dinv[r]   (64x128 tile, BK=16) ----
__global__ __launch_bounds__(256) void gemm_scale(
    const float* __restrict__ X, const float* __restrict__ W,
    const float* __restrict__ dinv, float* __restrict__ out, int n) {
  __shared__ float sXT[16][64];
  __shared__ float sW[16][H];
  int tid = threadIdx.x;
  int row0 = blockIdx.x * 64;
  int rg = tid >> 5;
  int cg = (tid & 31) << 2;

  float acc[8][4];
#pragma unroll
  for (int r = 0; r < 8; ++r) { acc[r][0]=0.f; acc[r][1]=0.f; acc[r][2]=0.f; acc[r][3]=0.f; }

  int xrow = tid >> 2;
  int xkq  = (tid & 3) << 2;
  int wkk  = tid >> 4;
  int wc   = (tid & 15) << 3;

  for (int k0 = 0; k0 < H; k0 += 16) {
    {
      int r = row0 + xrow;
      float4 v = make_float4(0.f, 0.f, 0.f, 0.f);
      if (r < n) v = *(const float4*)(X + (size_t)r * H + k0 + xkq);
      sXT[xkq + 0][xrow] = v.x;
      sXT[xkq + 1][xrow] = v.y;
      sXT[xkq + 2][xrow] = v.z;
      sXT[xkq + 3][xrow] = v.w;
    }
    {
      const float* wp = W + (size_t)(k0 + wkk) * H + wc;
      *(float4*)&sW[wkk][wc]     = *(const float4*)(wp);
      *(float4*)&sW[wkk][wc + 4] = *(const float4*)(wp + 4);
    }
    __syncthreads();
#pragma unroll
    for (int kk = 0; kk < 16; ++kk) {
      float4 wv = *(float4*)&sW[kk][cg];
      float4 a0 = *(float4*)&sXT[kk][rg * 8];
      float4 a1 = *(float4*)&sXT[kk][rg * 8 + 4];
      acc[0][0] = fmaf(a0.x, wv.x, acc[0][0]); acc[0][1] = fmaf(a0.x, wv.y, acc[0][1]);
      acc[0][2] = fmaf(a0.x, wv.z, acc[0][2]); acc[0][3] = fmaf(a0.x, wv.w, acc[0][3]);
      acc[1][0] = fmaf(a0.y, wv.x, acc[1][0]); acc[1][1] = fmaf(a0.y, wv.y, acc[1][1]);
      acc[1][2] = fmaf(a0.y, wv.z, acc[1][2]); acc[1][3] = fmaf(a0.y, wv.w, acc[1][3]);
      acc[2][0] = fmaf(a0.z, wv.x, acc[2][0]); acc[2][1] = fmaf(a0.z, wv.y, acc[2][1]);
      acc[2][2] = fmaf(a0.z, wv.z, acc[2][2]); acc[2][3] = fmaf(a0.z, wv.w, acc[2][3]);
      acc[3][0] = fmaf(a0.w, wv.x, acc[3][0]); acc[3][1] = fmaf(a0.w, wv.y, acc[3][1]);
      acc[3][2] = fmaf(a0.w, wv.z, acc[3][2]); acc[3][3] = fmaf(a0.w, wv.w, acc[3][3]);
      acc[4][0] = fmaf(a1.x, wv.x, acc[4][0]); acc[4][1] = fmaf(a1.x, wv.y, acc[4][1]);
      acc[4][2] = fmaf(a1.x, wv.z, acc[4][2]); acc[4][3] = fmaf(a1.x, wv.w, acc[4][3]);
      acc[5][0] = fmaf(a1.y, wv.x, acc[5][0]); acc[5][1] = fmaf(a1.y, wv.y, acc[5][1]);
      acc[5][2] = fmaf(a1.y, wv.z, acc[5][2]); acc[5][3] = fmaf(a1.y, wv.w, acc[5][3]);
      acc[6][0] = fmaf(a1.z, wv.x, acc[6][0]); acc[6][1] = fmaf(a1.z, wv.y, acc[6][1]);
      acc[6][2] = fmaf(a1.z, wv.z, acc[6][2]); acc[6][3] = fmaf(a1.z, wv.w, acc[6][3]);
      acc[7][0] = fmaf(a1.w, wv.x, acc[7][0]); acc[7][1] = fmaf(a1.w, wv.y, acc[7][1]);
      acc[7][2] = fmaf(a1.w, wv.z, acc[7][2]); acc[7][3] = fmaf(a1.w, wv.w, acc[7][3]);
    }
    __syncthreads();
  }
#pragma unroll
  for (int r = 0; r < 8; ++r) {
    int row = row0 + rg * 8 + r;
    if (row < n) {
      float dv = dinv[row];
      float4 o;
      o.x = acc[r][0] * dv; o.y = acc[r][1] * dv;
      o.z = acc[r][2] * dv; o.w = acc[r][3] * dv;
      *(float4*)(out + (size_t)row * H + cg) = o;
    }
  }
}

// ---- aggregate v3: branchless padded-CSR gather with index prefetch ----
// CSR rows padded to multiple of 8; pad entries point at zero row (index n).
template <bool RELU>
__global__ __launch_bounds__(256) void aggregate3(
    const float* __restrict__ hs, const int* __restrict__ row_start,
    const int* __restrict__ csr_src, const float* __restrict__ dinv,
    const float* __restrict__ b, float* __restrict__ out, int n) {
  int node = blockIdx.x * 8 + (threadIdx.x >> 5);
  if (node >= n) return;
  int c = (threadIdx.x & 31) << 2;
  int beg = row_start[node];
  int end = row_start[node + 1];

  float4 acc = *(const float4*)(hs + (size_t)node * H + c);  // self-loop term

  int4 ia, ib;
  if (beg < end) {
    ia = *(const int4*)(csr_src + beg);      // 16B-aligned: beg % 8 == 0
    ib = *(const int4*)(csr_src + beg + 4);
  }
  for (int k = beg; k < end; k += 8) {
    int4 ca = ia, cb = ib;
    int kn = k + 8;
    if (kn < end) {                          // prefetch next iteration's indices
      ia = *(const int4*)(csr_src + kn);
      ib = *(const int4*)(csr_src + kn + 4);
    }
    float4 v0 = *(const float4*)(hs + (size_t)ca.x * H + c);
    float4 v1 = *(const float4*)(hs + (size_t)ca.y * H + c);
    float4 v2 = *(const float4*)(hs + (size_t)ca.z * H + c);
    float4 v3 = *(const float4*)(hs + (size_t)ca.w * H + c);
    float4 v4 = *(const float4*)(hs + (size_t)cb.x * H + c);
    float4 v5 = *(const float4*)(hs + (size_t)cb.y * H + c);
    float4 v6 = *(const float4*)(hs + (size_t)cb.z * H + c);
    float4 v7 = *(const float4*)(hs + (size_t)cb.w * H + c);
    acc.x += ((v0.x + v1.x) + (v2.x + v3.x)) + ((v4.x + v5.x) + (v6.x + v7.x));
    acc.y += ((v0.y + v1.y) + (v2.y + v3.y)) + ((v4.y + v5.y) + (v6.y + v7.y));
    acc.z += ((v0.z + v1.z) + (v2.z + v3.z)) + ((v4.z + v5.z) + (v6.z + v7.z));
    acc.w += ((v0.w + v1.w) + (v2.w + v3.w)) + ((v4.w + v5.w) + (v6.w + v7.w));
  }

  float dv = dinv[node];
  float4 bb = *(const float4*)(b + c);
  float4 o;
  o.x = fmaf(acc.x, dv, bb.x);
  o.y = fmaf(acc.y, dv, bb.y);
  o.z = fmaf(acc.z, dv, bb.z);
  o.w = fmaf(acc.w, dv, bb.w);
  if (RELU) {
    o.x = fmaxf(o.x, 0.f); o.y = fmaxf(o.y, 0.f);
    o.z = fmaxf(o.z, 0.f); o.w = fmaxf(o.w, 0.f);
  }
  *(float4*)(out + (size_t)node * H + c) = o;
}

// ---- segmented pooling, 2 blocks per graph (column halves) ----
__global__ __launch_bounds__(256) void pool2(
    const float* __restrict__ h, const int* __restrict__ g_start,
    float* __restrict__ gmean, float* __restrict__ gmax, int n) {
  __shared__ float ssum[16][64];
  __shared__ float smax[16][64];
  int g = blockIdx.x >> 1;
  int half = blockIdx.x & 1;
  int beg = g_start[g];
  int end = g_start[g + 1];
  int q = threadIdx.x >> 4;            // 0..15 row-group
  int c = (threadIdx.x & 15) << 2;     // 0..60 local col
  int cg = half * 64 + c;

  float4 s = make_float4(0.f, 0.f, 0.f, 0.f);
  float4 m = make_float4(-INFINITY, -INFINITY, -INFINITY, -INFINITY);
  for (int node = beg + q; node < end; node += 16) {
    float4 v = *(const float4*)(h + (size_t)node * H + cg);
    s.x += v.x; s.y += v.y; s.z += v.z; s.w += v.w;
    m.x = fmaxf(m.x, v.x); m.y = fmaxf(m.y, v.y);
    m.z = fmaxf(m.z, v.z); m.w = fmaxf(m.w, v.w);
  }
  *(float4*)&ssum[q][c] = s;
  *(float4*)&smax[q][c] = m;
  __syncthreads();

  int cnt = end - beg;
  int t = threadIdx.x;
  if (t < 64) {
    float tot = 0.f;
#pragma unroll
    for (int qq = 0; qq < 16; ++qq) tot += ssum[qq][t];
    gmean[(size_t)g * H + half * 64 + t] = tot / fmaxf((float)cnt, 1.0f);
  } else if (t < 128) {
    int cc = t - 64;
    float mx = -INFINITY;
#pragma unroll
    for (int qq = 0; qq < 16; ++qq) mx = fmaxf(mx, smax[qq][cc]);
    gmax[(size_t)g * H + half * 64 + cc] = (cnt == 0) ? 0.0f : mx;
  }
}

// ---- classifier: one block per graph ----
__global__ __launch_bounds__(128) void classify_kernel(
    const float* __restrict__ gmean, const float* __restrict__ gmax,
    const float* __restrict__ Wc1, const float* __restrict__ bc1,
    const float* __restrict__ Wc2, const float* __restrict__ bc2,
    float* __restrict__ out) {
  __shared__ float gv[2 * H];
  __shared__ float hid[H];
  int gid = blockIdx.x;
  int t = threadIdx.x;
  gv[t] = gmean[(size_t)gid * H + t];
  gv[H + t] = gmax[(size_t)gid * H + t];
  __syncthreads();
  float acc = 0.f;
#pragma unroll 8
  for (int k = 0; k < 2 * H; ++k) acc = fmaf(gv[k], Wc1[(size_t)k * H + t], acc);
  hid[t] = fmaxf(acc + bc1[t], 0.f);
  __syncthreads();
  if (t < 10) {
    float a2 = 0.f;
    for (int j = 0; j < H; ++j) a2 = fmaf(hid[j], Wc2[(size_t)j * 10 + t], a2);
    out[(size_t)gid * 10 + t] = a2 + bc2[t];
  }
}

extern "C" void kernel_launch(void* const* d_in, const int* in_sizes, int n_in,
                              void* d_out, int out_size, void* d_ws, size_t ws_size,
                              hipStream_t stream) {
  const float* x    = (const float*)d_in[0];
  const int* ei     = (const int*)d_in[1];
  const int* batch  = (const int*)d_in[2];
  const float* W1   = (const float*)d_in[3];
  const float* b1   = (const float*)d_in[4];
  const float* W2   = (const float*)d_in[5];
  const float* b2   = (const float*)d_in[6];
  const float* W3   = (const float*)d_in[7];
  const float* b3   = (const float*)d_in[8];
  const float* Wc1  = (const float*)d_in[9];
  const float* bc1  = (const float*)d_in[10];
  const float* Wc2  = (const float*)d_in[11];
  const float* bc2  = (const float*)d_in[12];
  float* out = (float*)d_out;

  const int n  = in_sizes[2];        // 100000 nodes
  const int ne = in_sizes[1] / 2;    // 1600000 edges
  const int G  = 512;
  const size_t NF = (size_t)(n + 1) * H;   // +1 dummy zero row

  const int* src = ei;
  const int* dst = ei + ne;

  // ---- workspace layout (csr_src right after B keeps it 16B-aligned) ----
  float* A = (float*)d_ws;
  float* B = A + NF;
  int*   csr_src = (int*)(B + NF);
  const int csr_cap = ne + 8 * n;           // padded-CSR upper bound
  char* p = (char*)(csr_src + csr_cap);
  int*      deg_cnt  = (int*)p;       p += (size_t)n * 4;
  float*    dinv     = (float*)p;     p += (size_t)n * 4;
  int*      row_start= (int*)p;       p += (size_t)(n + 1) * 4;
  int*      cursor   = (int*)p;       p += (size_t)n * 4;
  int*      partials = (int*)p;       p += (size_t)256 * 4;
  int*      g_start  = (int*)p;       p += (size_t)(G + 1) * 4;
  float*    gmean    = (float*)p;     p += (size_t)G * H * 4;
  float*    gmax     = (float*)p;     p += (size_t)G * H * 4;

  hipMemsetAsync(deg_cnt, 0, (size_t)n * 4, stream);
  zero_rows<<<1, 256, 0, stream>>>(A, B, n);
  {
    int cap4 = csr_cap / 4;
    csr_init<<<(cap4 + 255) / 256, 256, 0, stream>>>(csr_src, cap4, n);
  }

  // ---- CSR build (once, reused by all 3 layers) ----
  int range = (n + 7) / 8;
  deg_x<<<64 * 8, 256, 0, stream>>>(dst, deg_cnt, ne, range, 64);
  dinv_kernel<<<(n + 255) / 256, 256, 0, stream>>>(deg_cnt, dinv, n);
  int nb = (n + 1023) / 1024;
  scan1<<<nb, 256, 0, stream>>>(deg_cnt, row_start, partials, n);
  scan2<<<1, 256, 0, stream>>>(partials, nb);
  scan3<<<(n + 255) / 256, 256, 0, stream>>>(row_start, cursor, deg_cnt, partials, n);
  csr_fill_x<<<128 * 8, 256, 0, stream>>>(src, dst, cursor, csr_src, ne, range, 128);
  gstart_kernel<<<(n + 255) / 256, 256, 0, stream>>>(batch, g_start, n, G);

  const int tile_grid = (n + 63) / 64;
  const int node_grid = (n + 7) / 8;

  // ---- layer 1 ----
  gemm_scale<<<tile_grid, 256, 0, stream>>>(x, W1, dinv, A, n);
  aggregate3<true><<<node_grid, 256, 0, stream>>>(A, row_start, csr_src, dinv, b1, B, n);

  // ---- layer 2 ----
  gemm_scale<<<tile_grid, 256, 0, stream>>>(B, W2, dinv, A, n);
  aggregate3<true><<<node_grid, 256, 0, stream>>>(A, row_start, csr_src, dinv, b2, B, n);

  // ---- layer 3 (no relu) ----
  gemm_scale<<<tile_grid, 256, 0, stream>>>(B, W3, dinv, A, n);
  aggregate3<false><<<node_grid, 256, 0, stream>>>(A, row_start, csr_src, dinv, b3, B, n);

  // ---- pooling + classifier ----
  pool2<<<2 * G, 256, 0, stream>>>(B, g_start, gmean, gmax, n);
  classify_kernel<<<G, 128, 0, stream>>>(gmean, gmax, Wc1, bc1, Wc2, bc2, out);
}

// Round 8
// 592.708 us; speedup vs baseline: 1.4855x; 1.3334x over previous
//
#include <hip/hip_runtime.h>

#define H 128

typedef __attribute__((ext_vector_type(8))) short bf16x8;
typedef __attribute__((ext_vector_type(4))) float f32x4;

// ---- f32 -> bf16 RTNE ----
__device__ __forceinline__ unsigned short f2bf(float f) {
  unsigned u = __float_as_uint(f);
  unsigned r = u + 0x7FFFu + ((u >> 16) & 1u);
  return (unsigned short)(r >> 16);
}
__device__ __forceinline__ float bf2f(unsigned short s) {
  return __uint_as_float(((unsigned)s) << 16);
}

// ---- XCD-range-partitioned degree count ----
__global__ __launch_bounds__(256) void deg_x(
    const int* __restrict__ dst, int* __restrict__ cnt,
    int ne, int range, int slices) {
  int r = blockIdx.x & 7;
  int slice = blockIdx.x >> 3;
  int chunk = (ne + slices - 1) / slices;
  int beg = slice * chunk;
  int end = beg + chunk; if (end > ne) end = ne;
  int lo = r * range;
  int hi = lo + range;
  for (int e = beg + threadIdx.x; e < end; e += 256) {
    int d = dst[e];
    if (d >= lo && d < hi) atomicAdd(&cnt[d], 1);
  }
}

__global__ void dinv_kernel(const int* __restrict__ cnt, float* __restrict__ dinv, int n) {
  int i = blockIdx.x * blockDim.x + threadIdx.x;
  if (i < n) dinv[i] = rsqrtf((float)(cnt[i] + 1));
}

// ---- zero dummy rows: P_bf[n], Q_bf[n] (bf16), F1f[n] (f32) ----
__global__ void zero_misc(unsigned short* __restrict__ P, unsigned short* __restrict__ Q,
                          float* __restrict__ F1, int n) {
  int t = threadIdx.x;
  if (t < H) {
    P[(size_t)n * H + t] = 0;
    Q[(size_t)n * H + t] = 0;
    F1[(size_t)n * H + t] = 0.f;
  }
}

// ---- init padded CSR storage with dummy index n ----
__global__ void csr_init(int* __restrict__ csr_src, int cap4, int n) {
  int i = blockIdx.x * blockDim.x + threadIdx.x;
  if (i < cap4) *(int4*)(csr_src + i * 4) = make_int4(n, n, n, n);
}

// ---- cvt x -> bf16 ----
__global__ __launch_bounds__(256) void cvt_x(const float* __restrict__ x,
                                             unsigned short* __restrict__ xb, int total4) {
  int i = blockIdx.x * blockDim.x + threadIdx.x;
  if (i < total4) {
    float4 v = *(const float4*)(x + i * 4);
    ushort4 o;
    o.x = f2bf(v.x); o.y = f2bf(v.y); o.z = f2bf(v.z); o.w = f2bf(v.w);
    *(ushort4*)(xb + i * 4) = o;
  }
}

// ---- cvt 3 weight mats -> bf16 TRANSPOSED: Wt[c*128+k] = bf16(W[k*128+c]) ----
__global__ __launch_bounds__(256) void cvt_w(const float* __restrict__ W1,
                                             const float* __restrict__ W2,
                                             const float* __restrict__ W3,
                                             unsigned short* __restrict__ Wt) {
  int t = blockIdx.x * blockDim.x + threadIdx.x;   // 3*128*128 total
  if (t >= 3 * H * H) return;
  int w = t >> 14;
  int rem = t & (H * H - 1);
  int c = rem >> 7;
  int k = rem & 127;
  const float* W = (w == 0) ? W1 : (w == 1) ? W2 : W3;
  Wt[t] = f2bf(W[(size_t)k * H + c]);
}

// ---- exclusive scan over PADDED degrees (pad to multiple of 8), stage 1 ----
__global__ __launch_bounds__(256) void scan1(const int* __restrict__ in,
                                             int* __restrict__ out,
                                             int* __restrict__ partials, int n) {
  __shared__ int sdata[256];
  int base = blockIdx.x * 1024;
  int t = threadIdx.x;
  int v[4];
  int sum = 0;
#pragma unroll
  for (int j = 0; j < 4; ++j) {
    int idx = base + t * 4 + j;
    v[j] = (idx < n) ? ((in[idx] + 7) & ~7) : 0;
    sum += v[j];
  }
  sdata[t] = sum;
  __syncthreads();
  for (int off = 1; off < 256; off <<= 1) {
    int y = (t >= off) ? sdata[t - off] : 0;
    __syncthreads();
    sdata[t] += y;
    __syncthreads();
  }
  int excl = sdata[t] - sum;
  int run = excl;
#pragma unroll
  for (int j = 0; j < 4; ++j) {
    int idx = base + t * 4 + j;
    if (idx < n) out[idx] = run;
    run += v[j];
  }
  if (t == 255) partials[blockIdx.x] = sdata[255];
}

__global__ __launch_bounds__(256) void scan2(int* __restrict__ partials, int nb) {
  __shared__ int sdata[256];
  int t = threadIdx.x;
  int v = (t < nb) ? partials[t] : 0;
  sdata[t] = v;
  __syncthreads();
  for (int off = 1; off < 256; off <<= 1) {
    int y = (t >= off) ? sdata[t - off] : 0;
    __syncthreads();
    sdata[t] += y;
    __syncthreads();
  }
  if (t < nb) partials[t] = sdata[t] - v;
}

__global__ void scan3(int* __restrict__ out, int* __restrict__ cursor,
                      const int* __restrict__ deg, const int* __restrict__ partials,
                      int n) {
  int i = blockIdx.x * blockDim.x + threadIdx.x;
  if (i < n) {
    int v = out[i] + partials[i >> 10];
    out[i] = v;
    cursor[i] = v;
    if (i == n - 1) out[n] = v + ((deg[i] + 7) & ~7);
  }
}

// ---- CSR fill, XCD-partitioned by dst-range ----
__global__ __launch_bounds__(256) void csr_fill_x(
    const int* __restrict__ src, const int* __restrict__ dst,
    int* __restrict__ cursor, int* __restrict__ csr_src,
    int ne, int range, int slices) {
  int r = blockIdx.x & 7;
  int slice = blockIdx.x >> 3;
  int chunk = (ne + slices - 1) / slices;
  int beg = slice * chunk;
  int end = beg + chunk; if (end > ne) end = ne;
  int lo = r * range;
  int hi = lo + range;
  for (int e = beg + threadIdx.x; e < end; e += 256) {
    int d = dst[e];
    int s = src[e];
    if (d >= lo && d < hi) {
      int p = atomicAdd(&cursor[d], 1);
      csr_src[p] = s;
    }
  }
}

// ---- graph boundaries from sorted batch ----
__global__ void gstart_kernel(const int* __restrict__ batch, int* __restrict__ g_start,
                              int n, int G) {
  int i = blockIdx.x * blockDim.x + threadIdx.x;
  if (i >= n) return;
  int b = batch[i];
  int prev = (i == 0) ? -1 : batch[i - 1];
  for (int g = prev + 1; g <= b; ++g) g_start[g] = i;
  if (i == n - 1) {
    for (int g = b + 1; g <= G; ++g) g_start[g] = n;
  }
}

// ---- MFMA GEMM: out[r][:] = (A @ W)[r][:] * dinv[r]; A bf16, W bf16-transposed ----
// 64 rows/block, 4 waves, wave w -> rows w*16..+15. A-frags from global, W from LDS.
#define SWLD 136   // padded LDS stride (ushorts)
template <bool OUT_F32>
__global__ __launch_bounds__(256) void gemm_mfma(
    const unsigned short* __restrict__ Ab, const unsigned short* __restrict__ Wt,
    const float* __restrict__ dinv, void* __restrict__ outv, int n) {
  __shared__ unsigned short sW[H * SWLD];
  int tid = threadIdx.x;
  {
    // each thread copies one 64-ushort (128 B) half-row: 8 x int4
    int c = tid >> 1, hh = tid & 1;
    const int4* s = (const int4*)(Wt + (size_t)c * H + hh * 64);
    int4* d = (int4*)(sW + (size_t)c * SWLD + hh * 64);
#pragma unroll
    for (int i = 0; i < 8; ++i) d[i] = s[i];
  }
  __syncthreads();

  int wave = tid >> 6;
  int lane = tid & 63;
  int m = lane & 15;
  int quad = lane >> 4;
  int row = blockIdx.x * 64 + wave * 16 + m;
  bool rv = row < n;

  f32x4 acc[8];
#pragma unroll
  for (int t = 0; t < 8; ++t) acc[t] = (f32x4){0.f, 0.f, 0.f, 0.f};

  const unsigned short* arow = Ab + (size_t)(rv ? row : 0) * H;
#pragma unroll
  for (int k0 = 0; k0 < H; k0 += 32) {
    bf16x8 af;
    if (rv) af = *(const bf16x8*)(arow + k0 + quad * 8);
    else    af = (bf16x8){0, 0, 0, 0, 0, 0, 0, 0};
#pragma unroll
    for (int ct = 0; ct < 8; ++ct) {
      bf16x8 bfr = *(const bf16x8*)(sW + (size_t)(ct * 16 + m) * SWLD + k0 + quad * 8);
      acc[ct] = __builtin_amdgcn_mfma_f32_16x16x32_bf16(af, bfr, acc[ct], 0, 0, 0);
    }
  }

  // D layout: col = ct*16 + m, row = wave*16 + quad*4 + r
  int orow0 = blockIdx.x * 64 + wave * 16 + quad * 4;
#pragma unroll
  for (int r = 0; r < 4; ++r) {
    int orow = orow0 + r;
    if (orow < n) {
      float dv = dinv[orow];
      if (OUT_F32) {
        float* o = (float*)outv + (size_t)orow * H + m;
#pragma unroll
        for (int ct = 0; ct < 8; ++ct) o[ct * 16] = acc[ct][r] * dv;
      } else {
        unsigned short* o = (unsigned short*)outv + (size_t)orow * H + m;
#pragma unroll
        for (int ct = 0; ct < 8; ++ct) o[ct * 16] = f2bf(acc[ct][r] * dv);
      }
    }
  }
}

// ---- bf16 aggregate: out = relu(dinv*(gather+self)+b), bf16 in/out ----
__global__ __launch_bounds__(256) void aggregate_bf(
    const unsigned short* __restrict__ hs, const int* __restrict__ row_start,
    const int* __restrict__ csr_src, const float* __restrict__ dinv,
    const float* __restrict__ b, unsigned short* __restrict__ out, int n) {
  int node = blockIdx.x * 8 + (threadIdx.x >> 5);
  if (node >= n) return;
  int c = (threadIdx.x & 31) << 2;
  int beg = row_start[node];
  int end = row_start[node + 1];

  ushort4 sv = *(const ushort4*)(hs + (size_t)node * H + c);  // self row
  float4 acc;
  acc.x = bf2f(sv.x); acc.y = bf2f(sv.y); acc.z = bf2f(sv.z); acc.w = bf2f(sv.w);

  int4 ia, ib;
  if (beg < end) {
    ia = *(const int4*)(csr_src + beg);
    ib = *(const int4*)(csr_src + beg + 4);
  }
  for (int k = beg; k < end; k += 8) {
    int4 ca = ia, cb = ib;
    int kn = k + 8;
    if (kn < end) {
      ia = *(const int4*)(csr_src + kn);
      ib = *(const int4*)(csr_src + kn + 4);
    }
    ushort4 v0 = *(const ushort4*)(hs + (size_t)ca.x * H + c);
    ushort4 v1 = *(const ushort4*)(hs + (size_t)ca.y * H + c);
    ushort4 v2 = *(const ushort4*)(hs + (size_t)ca.z * H + c);
    ushort4 v3 = *(const ushort4*)(hs + (size_t)ca.w * H + c);
    ushort4 v4 = *(const ushort4*)(hs + (size_t)cb.x * H + c);
    ushort4 v5 = *(const ushort4*)(hs + (size_t)cb.y * H + c);
    ushort4 v6 = *(const ushort4*)(hs + (size_t)cb.z * H + c);
    ushort4 v7 = *(const ushort4*)(hs + (size_t)cb.w * H + c);
    acc.x += ((bf2f(v0.x) + bf2f(v1.x)) + (bf2f(v2.x) + bf2f(v3.x))) +
             ((bf2f(v4.x) + bf2f(v5.x)) + (bf2f(v6.x) + bf2f(v7.x)));
    acc.y += ((bf2f(v0.y) + bf2f(v1.y)) + (bf2f(v2.y) + bf2f(v3.y))) +
             ((bf2f(v4.y) + bf2f(v5.y)) + (bf2f(v6.y) + bf2f(v7.y)));
    acc.z += ((bf2f(v0.z) + bf2f(v1.z)) + (bf2f(v2.z) + bf2f(v3.z))) +
             ((bf2f(v4.z) + bf2f(v5.z)) + (bf2f(v6.z) + bf2f(v7.z)));
    acc.w += ((bf2f(v0.w) + bf2f(v1.w)) + (bf2f(v2.w) + bf2f(v3.w))) +
             ((bf2f(v4.w) + bf2f(v5.w)) + (bf2f(v6.w) + bf2f(v7.w)));
  }

  float dv = dinv[node];
  float4 bb = *(const float4*)(b + c);
  ushort4 o;
  o.x = f2bf(fmaxf(fmaf(acc.x, dv, bb.x), 0.f));
  o.y = f2bf(fmaxf(fmaf(acc.y, dv, bb.y), 0.f));
  o.z = f2bf(fmaxf(fmaf(acc.z, dv, bb.z), 0.f));
  o.w = f2bf(fmaxf(fmaf(acc.w, dv, bb.w), 0.f));
  *(ushort4*)(out + (size_t)node * H + c) = o;
}

// ---- f32 aggregate (final layer; no relu) ----
__global__ __launch_bounds__(256) void aggregate3(
    const float* __restrict__ hs, const int* __restrict__ row_start,
    const int* __restrict__ csr_src, const float* __restrict__ dinv,
    const float* __restrict__ b, float* __restrict__ out, int n) {
  int node = blockIdx.x * 8 + (threadIdx.x >> 5);
  if (node >= n) return;
  int c = (threadIdx.x & 31) << 2;
  int beg = row_start[node];
  int end = row_start[node + 1];

  float4 acc = *(const float4*)(hs + (size_t)node * H + c);

  int4 ia, ib;
  if (beg < end) {
    ia = *(const int4*)(csr_src + beg);
    ib = *(const int4*)(csr_src + beg + 4);
  }
  for (int k = beg; k < end; k += 8) {
    int4 ca = ia, cb = ib;
    int kn = k + 8;
    if (kn < end) {
      ia = *(const int4*)(csr_src + kn);
      ib = *(const int4*)(csr_src + kn + 4);
    }
    float4 v0 = *(const float4*)(hs + (size_t)ca.x * H + c);
    float4 v1 = *(const float4*)(hs + (size_t)ca.y * H + c);
    float4 v2 = *(const float4*)(hs + (size_t)ca.z * H + c);
    float4 v3 = *(const float4*)(hs + (size_t)ca.w * H + c);
    float4 v4 = *(const float4*)(hs + (size_t)cb.x * H + c);
    float4 v5 = *(const float4*)(hs + (size_t)cb.y * H + c);
    float4 v6 = *(const float4*)(hs + (size_t)cb.z * H + c);
    float4 v7 = *(const float4*)(hs + (size_t)cb.w * H + c);
    acc.x += ((v0.x + v1.x) + (v2.x + v3.x)) + ((v4.x + v5.x) + (v6.x + v7.x));
    acc.y += ((v0.y + v1.y) + (v2.y + v3.y)) + ((v4.y + v5.y) + (v6.y + v7.y));
    acc.z += ((v0.z + v1.z) + (v2.z + v3.z)) + ((v4.z + v5.z) + (v6.z + v7.z));
    acc.w += ((v0.w + v1.w) + (v2.w + v3.w)) + ((v4.w + v5.w) + (v6.w + v7.w));
  }

  float dv = dinv[node];
  float4 bb = *(const float4*)(b + c);
  float4 o;
  o.x = fmaf(acc.x, dv, bb.x);
  o.y = fmaf(acc.y, dv, bb.y);
  o.z = fmaf(acc.z, dv, bb.z);
  o.w = fmaf(acc.w, dv, bb.w);
  *(float4*)(out + (size_t)node * H + c) = o;
}

// ---- segmented pooling, 2 blocks per graph (column halves), f32 ----
__global__ __launch_bounds__(256) void pool2(
    const float* __restrict__ h, const int* __restrict__ g_start,
    float* __restrict__ gmean, float* __restrict__ gmax, int n) {
  __shared__ float ssum[16][64];
  __shared__ float smax[16][64];
  int g = blockIdx.x >> 1;
  int half = blockIdx.x & 1;
  int beg = g_start[g];
  int end = g_start[g + 1];
  int q = threadIdx.x >> 4;
  int c = (threadIdx.x & 15) << 2;
  int cg = half * 64 + c;

  float4 s = make_float4(0.f, 0.f, 0.f, 0.f);
  float4 m = make_float4(-INFINITY, -INFINITY, -INFINITY, -INFINITY);
  for (int node = beg + q; node < end; node += 16) {
    float4 v = *(const float4*)(h + (size_t)node * H + cg);
    s.x += v.x; s.y += v.y; s.z += v.z; s.w += v.w;
    m.x = fmaxf(m.x, v.x); m.y = fmaxf(m.y, v.y);
    m.z = fmaxf(m.z, v.z); m.w = fmaxf(m.w, v.w);
  }
  *(float4*)&ssum[q][c] = s;
  *(float4*)&smax[q][c] = m;
  __syncthreads();

  int cnt = end - beg;
  int t = threadIdx.x;
  if (t < 64) {
    float tot = 0.f;
#pragma unroll
    for (int qq = 0; qq < 16; ++qq) tot += ssum[qq][t];
    gmean[(size_t)g * H + half * 64 + t] = tot / fmaxf((float)cnt, 1.0f);
  } else if (t < 128) {
    int cc = t - 64;
    float mx = -INFINITY;
#pragma unroll
    for (int qq = 0; qq < 16; ++qq) mx = fmaxf(mx, smax[qq][cc]);
    gmax[(size_t)g * H + half * 64 + cc] = (cnt == 0) ? 0.0f : mx;
  }
}

// ---- classifier: one block per graph (f32) ----
__global__ __launch_bounds__(128) void classify_kernel(
    const float* __restrict__ gmean, const float* __restrict__ gmax,
    const float* __restrict__ Wc1, const float* __restrict__ bc1,
    const float* __restrict__ Wc2, const float* __restrict__ bc2,
    float* __restrict__ out) {
  __shared__ float gv[2 * H];
  __shared__ float hid[H];
  int gid = blockIdx.x;
  int t = threadIdx.x;
  gv[t] = gmean[(size_t)gid * H + t];
  gv[H + t] = gmax[(size_t)gid * H + t];
  __syncthreads();
  float acc = 0.f;
#pragma unroll 8
  for (int k = 0; k < 2 * H; ++k) acc = fmaf(gv[k], Wc1[(size_t)k * H + t], acc);
  hid[t] = fmaxf(acc + bc1[t], 0.f);
  __syncthreads();
  if (t < 10) {
    float a2 = 0.f;
    for (int j = 0; j < H; ++j) a2 = fmaf(hid[j], Wc2[(size_t)j * 10 + t], a2);
    out[(size_t)gid * 10 + t] = a2 + bc2[t];
  }
}

extern "C" void kernel_launch(void* const* d_in, const int* in_sizes, int n_in,
                              void* d_out, int out_size, void* d_ws, size_t ws_size,
                              hipStream_t stream) {
  const float* x    = (const float*)d_in[0];
  const int* ei     = (const int*)d_in[1];
  const int* batch  = (const int*)d_in[2];
  const float* W1   = (const float*)d_in[3];
  const float* b1   = (const float*)d_in[4];
  const float* W2   = (const float*)d_in[5];
  const float* b2   = (const float*)d_in[6];
  const float* W3   = (const float*)d_in[7];
  const float* b3   = (const float*)d_in[8];
  const float* Wc1  = (const float*)d_in[9];
  const float* bc1  = (const float*)d_in[10];
  const float* Wc2  = (const float*)d_in[11];
  const float* bc2  = (const float*)d_in[12];
  float* out = (float*)d_out;

  const int n  = in_sizes[2];        // 100000 nodes
  const int ne = in_sizes[1] / 2;    // 1600000 edges
  const int G  = 512;
  const size_t NFb = (size_t)(n + 1) * H;   // +1 dummy row

  const int* src = ei;
  const int* dst = ei + ne;

  // ---- workspace layout ----
  unsigned short* P_bf = (unsigned short*)d_ws;
  float*          F1f  = (float*)(P_bf + NFb);
  unsigned short* Q_bf = (unsigned short*)F1f;
  float*          F2f  = F1f + NFb;
  unsigned short* Xb   = (unsigned short*)F2f;
  int* csr_src = (int*)(F2f + NFb);
  const int csr_cap = ne + 8 * n;
  char* p = (char*)(csr_src + csr_cap);
  int*            deg_cnt  = (int*)p;            p += (size_t)n * 4;
  float*          dinv     = (float*)p;          p += (size_t)n * 4;
  int*            row_start= (int*)p;            p += (size_t)(n + 1) * 4;
  int*            cursor   = (int*)p;            p += (size_t)n * 4;
  int*            partials = (int*)p;            p += (size_t)256 * 4;
  int*            g_start  = (int*)p;            p += (size_t)(G + 1) * 4;
  float*          gmean    = (float*)p;          p += (size_t)G * H * 4;
  float*          gmax     = (float*)p;          p += (size_t)G * H * 4;
  p = (char*)(((uintptr_t)p + 255) & ~(uintptr_t)255);   // 256B-align Wt for int4 loads
  unsigned short* Wt       = (unsigned short*)p; p += (size_t)3 * H * H * 2;

  hipMemsetAsync(deg_cnt, 0, (size_t)n * 4, stream);
  zero_misc<<<1, 256, 0, stream>>>(P_bf, Q_bf, F1f, n);
  {
    int cap4 = csr_cap / 4;
    csr_init<<<(cap4 + 255) / 256, 256, 0, stream>>>(csr_src, cap4, n);
  }
  cvt_x<<<((n * H / 4) + 255) / 256, 256, 0, stream>>>(x, Xb, n * H / 4);
  cvt_w<<<(3 * H * H + 255) / 256, 256, 0, stream>>>(W1, W2, W3, Wt);

  // ---- CSR build ----
  int range = (n + 7) / 8;
  deg_x<<<64 * 8, 256, 0, stream>>>(dst, deg_cnt, ne, range, 64);
  dinv_kernel<<<(n + 255) / 256, 256, 0, stream>>>(deg_cnt, dinv, n);
  int nb = (n + 1023) / 1024;
  scan1<<<nb, 256, 0, stream>>>(deg_cnt, row_start, partials, n);
  scan2<<<1, 256, 0, stream>>>(partials, nb);
  scan3<<<(n + 255) / 256, 256, 0, stream>>>(row_start, cursor, deg_cnt, partials, n);
  csr_fill_x<<<128 * 8, 256, 0, stream>>>(src, dst, cursor, csr_src, ne, range, 128);
  gstart_kernel<<<(n + 255) / 256, 256, 0, stream>>>(batch, g_start, n, G);

  const int tile_grid = (n + 63) / 64;
  const int node_grid = (n + 7) / 8;

  // ---- layer 1: h'1 = (xb @ W1)*dinv (bf16) -> Q ; h1 = relu(agg)+b1 (bf16) -> P ----
  gemm_mfma<false><<<tile_grid, 256, 0, stream>>>(Xb, Wt, dinv, Q_bf, n);
  aggregate_bf<<<node_grid, 256, 0, stream>>>(Q_bf, row_start, csr_src, dinv, b1, P_bf, n);

  // ---- layer 2 ----
  gemm_mfma<false><<<tile_grid, 256, 0, stream>>>(P_bf, Wt + H * H, dinv, Q_bf, n);
  aggregate_bf<<<node_grid, 256, 0, stream>>>(Q_bf, row_start, csr_src, dinv, b2, P_bf, n);

  // ---- layer 3 (f32 path) ----
  gemm_mfma<true><<<tile_grid, 256, 0, stream>>>(P_bf, Wt + 2 * H * H, dinv, F1f, n);
  aggregate3<<<node_grid, 256, 0, stream>>>(F1f, row_start, csr_src, dinv, b3, F2f, n);

  // ---- pooling + classifier ----
  pool2<<<2 * G, 256, 0, stream>>>(F2f, g_start, gmean, gmax, n);
  classify_kernel<<<G, 128, 0, stream>>>(gmean, gmax, Wc1, bc1, Wc2, bc2, out);
}

// Round 9
// 524.997 us; speedup vs baseline: 1.6771x; 1.1290x over previous
//
#include <hip/hip_runtime.h>

#define H 128

typedef __attribute__((ext_vector_type(8))) short bf16x8;
typedef __attribute__((ext_vector_type(4))) float f32x4;

// ---- f32 -> bf16 RTNE ----
__device__ __forceinline__ unsigned short f2bf(float f) {
  unsigned u = __float_as_uint(f);
  unsigned r = u + 0x7FFFu + ((u >> 16) & 1u);
  return (unsigned short)(r >> 16);
}
__device__ __forceinline__ float bf2f(unsigned short s) {
  return __uint_as_float(((unsigned)s) << 16);
}

// ---- XCD-range-partitioned degree count ----
__global__ __launch_bounds__(256) void deg_x(
    const int* __restrict__ dst, int* __restrict__ cnt,
    int ne, int range, int slices) {
  int r = blockIdx.x & 7;
  int slice = blockIdx.x >> 3;
  int chunk = (ne + slices - 1) / slices;
  int beg = slice * chunk;
  int end = beg + chunk; if (end > ne) end = ne;
  int lo = r * range;
  int hi = lo + range;
  for (int e = beg + threadIdx.x; e < end; e += 256) {
    int d = dst[e];
    if (d >= lo && d < hi) atomicAdd(&cnt[d], 1);
  }
}

// ---- merged setup: cvt x->bf16 | csr_init | cvt_w (transposed) | zero dummy rows ----
__global__ __launch_bounds__(256) void setup_all(
    const float* __restrict__ x,
    const float* __restrict__ W1, const float* __restrict__ W2, const float* __restrict__ W3,
    unsigned short* __restrict__ Xb, unsigned short* __restrict__ Wt,
    int* __restrict__ csr_src, int cap4,
    unsigned short* __restrict__ P, unsigned short* __restrict__ Q,
    int n, int totalX4) {
  long long i = (long long)blockIdx.x * 256 + threadIdx.x;
  if (i < totalX4) {                     // x -> bf16 (4 elems/thread)
    float4 v = *(const float4*)(x + i * 4);
    ushort4 o;
    o.x = f2bf(v.x); o.y = f2bf(v.y); o.z = f2bf(v.z); o.w = f2bf(v.w);
    *(ushort4*)(Xb + i * 4) = o;
    return;
  }
  i -= totalX4;
  if (i < cap4) {                        // padded-CSR init with dummy index n
    *(int4*)(csr_src + i * 4) = make_int4(n, n, n, n);
    return;
  }
  i -= cap4;
  if (i < 3 * H * H) {                   // W -> bf16 transposed
    int w = (int)(i >> 14);
    int rem = (int)i & (H * H - 1);
    int c = rem >> 7;
    int k = rem & 127;
    const float* W = (w == 0) ? W1 : (w == 1) ? W2 : W3;
    Wt[i] = f2bf(W[(size_t)k * H + c]);
    return;
  }
  i -= 3 * H * H;
  if (i < H) {                           // zero dummy rows (gather target index n)
    P[(size_t)n * H + i] = 0;
    Q[(size_t)n * H + i] = 0;
  }
}

// ---- exclusive scan over PADDED degrees (pad to multiple of 8), stage 1 ----
__global__ __launch_bounds__(256) void scan1(const int* __restrict__ in,
                                             int* __restrict__ out,
                                             int* __restrict__ partials, int n) {
  __shared__ int sdata[256];
  int base = blockIdx.x * 1024;
  int t = threadIdx.x;
  int v[4];
  int sum = 0;
#pragma unroll
  for (int j = 0; j < 4; ++j) {
    int idx = base + t * 4 + j;
    v[j] = (idx < n) ? ((in[idx] + 7) & ~7) : 0;
    sum += v[j];
  }
  sdata[t] = sum;
  __syncthreads();
  for (int off = 1; off < 256; off <<= 1) {
    int y = (t >= off) ? sdata[t - off] : 0;
    __syncthreads();
    sdata[t] += y;
    __syncthreads();
  }
  int excl = sdata[t] - sum;
  int run = excl;
#pragma unroll
  for (int j = 0; j < 4; ++j) {
    int idx = base + t * 4 + j;
    if (idx < n) out[idx] = run;
    run += v[j];
  }
  if (t == 255) partials[blockIdx.x] = sdata[255];
}

__global__ __launch_bounds__(256) void scan2(int* __restrict__ partials, int nb) {
  __shared__ int sdata[256];
  int t = threadIdx.x;
  int v = (t < nb) ? partials[t] : 0;
  sdata[t] = v;
  __syncthreads();
  for (int off = 1; off < 256; off <<= 1) {
    int y = (t >= off) ? sdata[t - off] : 0;
    __syncthreads();
    sdata[t] += y;
    __syncthreads();
  }
  if (t < nb) partials[t] = sdata[t] - v;
}

// ---- scan3: add block offsets, dup cursor, total, AND dinv ----
__global__ void scan3(int* __restrict__ out, int* __restrict__ cursor,
                      const int* __restrict__ deg, const int* __restrict__ partials,
                      float* __restrict__ dinv, int n) {
  int i = blockIdx.x * blockDim.x + threadIdx.x;
  if (i < n) {
    int v = out[i] + partials[i >> 10];
    out[i] = v;
    cursor[i] = v;
    dinv[i] = rsqrtf((float)(deg[i] + 1));
    if (i == n - 1) out[n] = v + ((deg[i] + 7) & ~7);
  }
}

// ---- CSR fill, XCD-partitioned by dst-range ----
__global__ __launch_bounds__(256) void csr_fill_x(
    const int* __restrict__ src, const int* __restrict__ dst,
    int* __restrict__ cursor, int* __restrict__ csr_src,
    int ne, int range, int slices) {
  int r = blockIdx.x & 7;
  int slice = blockIdx.x >> 3;
  int chunk = (ne + slices - 1) / slices;
  int beg = slice * chunk;
  int end = beg + chunk; if (end > ne) end = ne;
  int lo = r * range;
  int hi = lo + range;
  for (int e = beg + threadIdx.x; e < end; e += 256) {
    int d = dst[e];
    int s = src[e];
    if (d >= lo && d < hi) {
      int p = atomicAdd(&cursor[d], 1);
      csr_src[p] = s;
    }
  }
}

// ---- graph boundaries from sorted batch ----
__global__ void gstart_kernel(const int* __restrict__ batch, int* __restrict__ g_start,
                              int n, int G) {
  int i = blockIdx.x * blockDim.x + threadIdx.x;
  if (i >= n) return;
  int b = batch[i];
  int prev = (i == 0) ? -1 : batch[i - 1];
  for (int g = prev + 1; g <= b; ++g) g_start[g] = i;
  if (i == n - 1) {
    for (int g = b + 1; g <= G; ++g) g_start[g] = n;
  }
}

// ---- MFMA GEMM: out[r][:] = bf16((A @ W)[r][:] * dinv[r]); A bf16, W bf16^T ----
#define SWLD 136
__global__ __launch_bounds__(256) void gemm_mfma(
    const unsigned short* __restrict__ Ab, const unsigned short* __restrict__ Wt,
    const float* __restrict__ dinv, unsigned short* __restrict__ outb, int n) {
  __shared__ unsigned short sW[H * SWLD];
  int tid = threadIdx.x;
  {
    int c = tid >> 1, hh = tid & 1;
    const int4* s = (const int4*)(Wt + (size_t)c * H + hh * 64);
    int4* d = (int4*)(sW + (size_t)c * SWLD + hh * 64);
#pragma unroll
    for (int i = 0; i < 8; ++i) d[i] = s[i];
  }
  __syncthreads();

  int wave = tid >> 6;
  int lane = tid & 63;
  int m = lane & 15;
  int quad = lane >> 4;
  int row = blockIdx.x * 64 + wave * 16 + m;
  bool rv = row < n;

  f32x4 acc[8];
#pragma unroll
  for (int t = 0; t < 8; ++t) acc[t] = (f32x4){0.f, 0.f, 0.f, 0.f};

  const unsigned short* arow = Ab + (size_t)(rv ? row : 0) * H;
#pragma unroll
  for (int k0 = 0; k0 < H; k0 += 32) {
    bf16x8 af;
    if (rv) af = *(const bf16x8*)(arow + k0 + quad * 8);
    else    af = (bf16x8){0, 0, 0, 0, 0, 0, 0, 0};
#pragma unroll
    for (int ct = 0; ct < 8; ++ct) {
      bf16x8 bfr = *(const bf16x8*)(sW + (size_t)(ct * 16 + m) * SWLD + k0 + quad * 8);
      acc[ct] = __builtin_amdgcn_mfma_f32_16x16x32_bf16(af, bfr, acc[ct], 0, 0, 0);
    }
  }

  int orow0 = blockIdx.x * 64 + wave * 16 + quad * 4;
#pragma unroll
  for (int r = 0; r < 4; ++r) {
    int orow = orow0 + r;
    if (orow < n) {
      float dv = dinv[orow];
      unsigned short* o = outb + (size_t)orow * H + m;
#pragma unroll
      for (int ct = 0; ct < 8; ++ct) o[ct * 16] = f2bf(acc[ct][r] * dv);
    }
  }
}

// ---- bf16-input aggregate; f32 accumulate; bf16 or f32 out ----
template <bool RELU, bool OUTF32>
__global__ __launch_bounds__(256) void aggregate_bf(
    const unsigned short* __restrict__ hs, const int* __restrict__ row_start,
    const int* __restrict__ csr_src, const float* __restrict__ dinv,
    const float* __restrict__ b, void* __restrict__ outv, int n) {
  int node = blockIdx.x * 8 + (threadIdx.x >> 5);
  if (node >= n) return;
  int c = (threadIdx.x & 31) << 2;
  int beg = row_start[node];
  int end = row_start[node + 1];

  ushort4 sv = *(const ushort4*)(hs + (size_t)node * H + c);  // self row
  float4 acc;
  acc.x = bf2f(sv.x); acc.y = bf2f(sv.y); acc.z = bf2f(sv.z); acc.w = bf2f(sv.w);

  int4 ia, ib;
  if (beg < end) {
    ia = *(const int4*)(csr_src + beg);
    ib = *(const int4*)(csr_src + beg + 4);
  }
  for (int k = beg; k < end; k += 8) {
    int4 ca = ia, cb = ib;
    int kn = k + 8;
    if (kn < end) {
      ia = *(const int4*)(csr_src + kn);
      ib = *(const int4*)(csr_src + kn + 4);
    }
    ushort4 v0 = *(const ushort4*)(hs + (size_t)ca.x * H + c);
    ushort4 v1 = *(const ushort4*)(hs + (size_t)ca.y * H + c);
    ushort4 v2 = *(const ushort4*)(hs + (size_t)ca.z * H + c);
    ushort4 v3 = *(const ushort4*)(hs + (size_t)ca.w * H + c);
    ushort4 v4 = *(const ushort4*)(hs + (size_t)cb.x * H + c);
    ushort4 v5 = *(const ushort4*)(hs + (size_t)cb.y * H + c);
    ushort4 v6 = *(const ushort4*)(hs + (size_t)cb.z * H + c);
    ushort4 v7 = *(const ushort4*)(hs + (size_t)cb.w * H + c);
    acc.x += ((bf2f(v0.x) + bf2f(v1.x)) + (bf2f(v2.x) + bf2f(v3.x))) +
             ((bf2f(v4.x) + bf2f(v5.x)) + (bf2f(v6.x) + bf2f(v7.x)));
    acc.y += ((bf2f(v0.y) + bf2f(v1.y)) + (bf2f(v2.y) + bf2f(v3.y))) +
             ((bf2f(v4.y) + bf2f(v5.y)) + (bf2f(v6.y) + bf2f(v7.y)));
    acc.z += ((bf2f(v0.z) + bf2f(v1.z)) + (bf2f(v2.z) + bf2f(v3.z))) +
             ((bf2f(v4.z) + bf2f(v5.z)) + (bf2f(v6.z) + bf2f(v7.z)));
    acc.w += ((bf2f(v0.w) + bf2f(v1.w)) + (bf2f(v2.w) + bf2f(v3.w))) +
             ((bf2f(v4.w) + bf2f(v5.w)) + (bf2f(v6.w) + bf2f(v7.w)));
  }

  float dv = dinv[node];
  float4 bb = *(const float4*)(b + c);
  float4 o;
  o.x = fmaf(acc.x, dv, bb.x);
  o.y = fmaf(acc.y, dv, bb.y);
  o.z = fmaf(acc.z, dv, bb.z);
  o.w = fmaf(acc.w, dv, bb.w);
  if (RELU) {
    o.x = fmaxf(o.x, 0.f); o.y = fmaxf(o.y, 0.f);
    o.z = fmaxf(o.z, 0.f); o.w = fmaxf(o.w, 0.f);
  }
  if (OUTF32) {
    *(float4*)((float*)outv + (size_t)node * H + c) = o;
  } else {
    ushort4 ob;
    ob.x = f2bf(o.x); ob.y = f2bf(o.y); ob.z = f2bf(o.z); ob.w = f2bf(o.w);
    *(ushort4*)((unsigned short*)outv + (size_t)node * H + c) = ob;
  }
}

// ---- segmented pooling, 2 blocks per graph (column halves), f32 ----
__global__ __launch_bounds__(256) void pool2(
    const float* __restrict__ h, const int* __restrict__ g_start,
    float* __restrict__ gmean, float* __restrict__ gmax, int n) {
  __shared__ float ssum[16][64];
  __shared__ float smax[16][64];
  int g = blockIdx.x >> 1;
  int half = blockIdx.x & 1;
  int beg = g_start[g];
  int end = g_start[g + 1];
  int q = threadIdx.x >> 4;
  int c = (threadIdx.x & 15) << 2;
  int cg = half * 64 + c;

  float4 s = make_float4(0.f, 0.f, 0.f, 0.f);
  float4 m = make_float4(-INFINITY, -INFINITY, -INFINITY, -INFINITY);
  for (int node = beg + q; node < end; node += 16) {
    float4 v = *(const float4*)(h + (size_t)node * H + cg);
    s.x += v.x; s.y += v.y; s.z += v.z; s.w += v.w;
    m.x = fmaxf(m.x, v.x); m.y = fmaxf(m.y, v.y);
    m.z = fmaxf(m.z, v.z); m.w = fmaxf(m.w, v.w);
  }
  *(float4*)&ssum[q][c] = s;
  *(float4*)&smax[q][c] = m;
  __syncthreads();

  int cnt = end - beg;
  int t = threadIdx.x;
  if (t < 64) {
    float tot = 0.f;
#pragma unroll
    for (int qq = 0; qq < 16; ++qq) tot += ssum[qq][t];
    gmean[(size_t)g * H + half * 64 + t] = tot / fmaxf((float)cnt, 1.0f);
  } else if (t < 128) {
    int cc = t - 64;
    float mx = -INFINITY;
#pragma unroll
    for (int qq = 0; qq < 16; ++qq) mx = fmaxf(mx, smax[qq][cc]);
    gmax[(size_t)g * H + half * 64 + cc] = (cnt == 0) ? 0.0f : mx;
  }
}

// ---- classifier: one block per graph (f32) ----
__global__ __launch_bounds__(128) void classify_kernel(
    const float* __restrict__ gmean, const float* __restrict__ gmax,
    const float* __restrict__ Wc1, const float* __restrict__ bc1,
    const float* __restrict__ Wc2, const float* __restrict__ bc2,
    float* __restrict__ out) {
  __shared__ float gv[2 * H];
  __shared__ float hid[H];
  int gid = blockIdx.x;
  int t = threadIdx.x;
  gv[t] = gmean[(size_t)gid * H + t];
  gv[H + t] = gmax[(size_t)gid * H + t];
  __syncthreads();
  float acc = 0.f;
#pragma unroll 8
  for (int k = 0; k < 2 * H; ++k) acc = fmaf(gv[k], Wc1[(size_t)k * H + t], acc);
  hid[t] = fmaxf(acc + bc1[t], 0.f);
  __syncthreads();
  if (t < 10) {
    float a2 = 0.f;
    for (int j = 0; j < H; ++j) a2 = fmaf(hid[j], Wc2[(size_t)j * 10 + t], a2);
    out[(size_t)gid * 10 + t] = a2 + bc2[t];
  }
}

extern "C" void kernel_launch(void* const* d_in, const int* in_sizes, int n_in,
                              void* d_out, int out_size, void* d_ws, size_t ws_size,
                              hipStream_t stream) {
  const float* x    = (const float*)d_in[0];
  const int* ei     = (const int*)d_in[1];
  const int* batch  = (const int*)d_in[2];
  const float* W1   = (const float*)d_in[3];
  const float* b1   = (const float*)d_in[4];
  const float* W2   = (const float*)d_in[5];
  const float* b2   = (const float*)d_in[6];
  const float* W3   = (const float*)d_in[7];
  const float* b3   = (const float*)d_in[8];
  const float* Wc1  = (const float*)d_in[9];
  const float* bc1  = (const float*)d_in[10];
  const float* Wc2  = (const float*)d_in[11];
  const float* bc2  = (const float*)d_in[12];
  float* out = (float*)d_out;

  const int n  = in_sizes[2];        // 100000 nodes
  const int ne = in_sizes[1] / 2;    // 1600000 edges
  const int G  = 512;
  const size_t NFb = (size_t)(n + 1) * H;   // +1 dummy row (bf16 tables)

  const int* src = ei;
  const int* dst = ei + ne;

  // ---- workspace layout ----
  unsigned short* P_bf = (unsigned short*)d_ws;          // h (post-agg) bf16
  unsigned short* Q_bf = P_bf + NFb;                      // h' (post-gemm) bf16
  float*          F2f  = (float*)(Q_bf + NFb);            // final h3 f32
  unsigned short* Xb   = (unsigned short*)F2f;            // x bf16 (aliases F2f)
  int* csr_src = (int*)(F2f + (size_t)n * H);
  const int csr_cap = ne + 8 * n;
  char* p = (char*)(csr_src + csr_cap);
  int*            deg_cnt  = (int*)p;            p += (size_t)n * 4;
  float*          dinv     = (float*)p;          p += (size_t)n * 4;
  int*            row_start= (int*)p;            p += (size_t)(n + 1) * 4;
  int*            cursor   = (int*)p;            p += (size_t)n * 4;
  int*            partials = (int*)p;            p += (size_t)256 * 4;
  int*            g_start  = (int*)p;            p += (size_t)(G + 1) * 4;
  float*          gmean    = (float*)p;          p += (size_t)G * H * 4;
  float*          gmax     = (float*)p;          p += (size_t)G * H * 4;
  p = (char*)(((uintptr_t)p + 255) & ~(uintptr_t)255);   // align Wt for int4 loads
  unsigned short* Wt       = (unsigned short*)p; p += (size_t)3 * H * H * 2;

  hipMemsetAsync(deg_cnt, 0, (size_t)n * 4, stream);

  // ---- merged setup ----
  {
    int totalX4 = n * H / 4;
    int cap4 = csr_cap / 4;
    long long tot = (long long)totalX4 + cap4 + 3 * H * H + H;
    int blocks = (int)((tot + 255) / 256);
    setup_all<<<blocks, 256, 0, stream>>>(x, W1, W2, W3, Xb, Wt, csr_src, cap4,
                                          P_bf, Q_bf, n, totalX4);
  }

  // ---- CSR build ----
  int range = (n + 7) / 8;
  deg_x<<<64 * 8, 256, 0, stream>>>(dst, deg_cnt, ne, range, 64);
  int nb = (n + 1023) / 1024;
  scan1<<<nb, 256, 0, stream>>>(deg_cnt, row_start, partials, n);
  scan2<<<1, 256, 0, stream>>>(partials, nb);
  scan3<<<(n + 255) / 256, 256, 0, stream>>>(row_start, cursor, deg_cnt, partials, dinv, n);
  csr_fill_x<<<128 * 8, 256, 0, stream>>>(src, dst, cursor, csr_src, ne, range, 128);
  gstart_kernel<<<(n + 255) / 256, 256, 0, stream>>>(batch, g_start, n, G);

  const int tile_grid = (n + 63) / 64;
  const int node_grid = (n + 7) / 8;

  // ---- layer 1 ----
  gemm_mfma<<<tile_grid, 256, 0, stream>>>(Xb, Wt, dinv, Q_bf, n);
  aggregate_bf<true, false><<<node_grid, 256, 0, stream>>>(Q_bf, row_start, csr_src, dinv, b1, P_bf, n);

  // ---- layer 2 ----
  gemm_mfma<<<tile_grid, 256, 0, stream>>>(P_bf, Wt + H * H, dinv, Q_bf, n);
  aggregate_bf<true, false><<<node_grid, 256, 0, stream>>>(Q_bf, row_start, csr_src, dinv, b2, P_bf, n);

  // ---- layer 3: bf16 gather, f32 output, no relu ----
  gemm_mfma<<<tile_grid, 256, 0, stream>>>(P_bf, Wt + 2 * H * H, dinv, Q_bf, n);
  aggregate_bf<false, true><<<node_grid, 256, 0, stream>>>(Q_bf, row_start, csr_src, dinv, b3, F2f, n);

  // ---- pooling + classifier ----
  pool2<<<2 * G, 256, 0, stream>>>(F2f, g_start, gmean, gmax, n);
  classify_kernel<<<G, 128, 0, stream>>>(gmean, gmax, Wc1, bc1, Wc2, bc2, out);
}